// Round 5
// baseline (430.275 us; speedup 1.0000x reference)
//
#include <hip/hip_runtime.h>

typedef int v4i __attribute__((ext_vector_type(4)));
typedef int v16i __attribute__((ext_vector_type(16)));

#define EPS_F 1e-8f

#define GLOAD_LDS16(g, l)                                              \
    __builtin_amdgcn_global_load_lds(                                  \
        (const __attribute__((address_space(1))) void*)(g),            \
        (__attribute__((address_space(3))) void*)(l), 16, 0, 0)

// ---------------- kernel 1: fused |w|-sum (blocks [0,1024)) + per-token x quant ----------------
__global__ void __launch_bounds__(256) wabs_xquant_kernel(const float* __restrict__ w,
                                                          double* __restrict__ out, int n4,
                                                          const float* __restrict__ x,
                                                          signed char* __restrict__ xq,
                                                          float* __restrict__ xscale, int K) {
    if (blockIdx.x < 1024) {
        // ---- |w| fp64 sum ----
        const float4* w4 = (const float4*)w;
        double s = 0.0;
        int idx = blockIdx.x * 256 + threadIdx.x;
        int stride = 1024 * 256;
        for (int i = idx; i < n4; i += stride) {
            float4 v = w4[i];
            s += (double)fabsf(v.x) + (double)fabsf(v.y) +
                 (double)fabsf(v.z) + (double)fabsf(v.w);
        }
        for (int off = 32; off > 0; off >>= 1)
            s += __shfl_down(s, off);
        __shared__ double smd[4];
        if ((threadIdx.x & 63) == 0) smd[threadIdx.x >> 6] = s;
        __syncthreads();
        if (threadIdx.x == 0) {
            atomicAdd(out, smd[0] + smd[1] + smd[2] + smd[3]);
        }
    } else {
        // ---- per-token int8 activation quant, one row per block ----
        int row = blockIdx.x - 1024;
        const float4* xr = (const float4*)(x + (size_t)row * K);
        unsigned int* qr = (unsigned int*)(xq + (size_t)row * K);
        int t = threadIdx.x;
        float4 v[4];
        float mx = 0.0f;
#pragma unroll
        for (int j = 0; j < 4; j++) {
            v[j] = xr[t + j * 256];
            mx = fmaxf(mx, fmaxf(fmaxf(fabsf(v[j].x), fabsf(v[j].y)),
                                 fmaxf(fabsf(v[j].z), fabsf(v[j].w))));
        }
        for (int off = 32; off > 0; off >>= 1)
            mx = fmaxf(mx, __shfl_down(mx, off));
        __shared__ float smf[4];
        if ((t & 63) == 0) smf[t >> 6] = mx;
        __syncthreads();
        float scale = fmaxf(fmaxf(fmaxf(smf[0], smf[1]), fmaxf(smf[2], smf[3])), EPS_F);
        float inv = 127.0f / scale;
#pragma unroll
        for (int j = 0; j < 4; j++) {
            int q0 = min(127, max(-127, (int)rintf(v[j].x * inv)));
            int q1 = min(127, max(-127, (int)rintf(v[j].y * inv)));
            int q2 = min(127, max(-127, (int)rintf(v[j].z * inv)));
            int q3 = min(127, max(-127, (int)rintf(v[j].w * inv)));
            qr[t + j * 256] = (q0 & 0xff) | ((q1 & 0xff) << 8) | ((q2 & 0xff) << 16) | ((q3 & 0xff) << 24);
        }
        if (t == 0) xscale[row] = scale;
    }
}

// ---------------- kernel 2: ternary-quantize W -> int8 ----------------
__global__ void __launch_bounds__(256) wquant_kernel(const float* __restrict__ w,
                                                     const double* __restrict__ wsum,
                                                     signed char* __restrict__ wq,
                                                     int n4, int n) {
    float wsf = (float)(wsum[0] / (double)n) + EPS_F;
    float inv = 1.0f / wsf;
    const float4* w4 = (const float4*)w;
    unsigned int* q4 = (unsigned int*)wq;
    int idx = blockIdx.x * 256 + threadIdx.x;
    int stride = gridDim.x * 256;
    for (int i = idx; i < n4; i += stride) {
        float4 v = w4[i];
        int q0 = min(1, max(-1, (int)rintf(v.x * inv)));
        int q1 = min(1, max(-1, (int)rintf(v.y * inv)));
        int q2 = min(1, max(-1, (int)rintf(v.z * inv)));
        int q3 = min(1, max(-1, (int)rintf(v.w * inv)));
        q4[i] = (q0 & 0xff) | ((q1 & 0xff) << 8) | ((q2 & 0xff) << 16) | ((q3 & 0xff) << 24);
    }
}

// ---------------- kernel 3: int8 MFMA GEMM, 256x256, 4-phase + B-reg double-buffer ----------------
// 512 threads = 8 waves (2M x 4N). Per-wave output 128x64 = 4x2 tiles of 32x32.
// BK=128. LDS: [buf(2)][A/B][khalf(2)] regions of 16KB = 128KB (1 block/CU).
// Region layout: seg(row,c) = row*4 + (c ^ ((row>>1)&3)) -> conflict-free ds_read_b128.
//
// r4 post-mortem: phase = 3019 cyc vs pipe needs {MFMA 1171, LDS ~1500} -- the
// read convoy (all waves' ds_reads after the barrier, MFMAs dependent on them)
// serialized LDS then MFMA. Fix: B-fragment register double-buffer (+16 VGPR,
// fits 256-reg budget at 2 waves/SIMD; A-frags can't fit): phase k pre-reads
// the NEXT phase's 4 B-frags; MFMAs of phase k need only their first A-read to
// start, and A-reads (8/wave) flow concurrently with the MFMA stream (LDS
// serves one read per ~12 cyc; MFMA consumes one per ~73 cyc).
// Ledger (vmcnt(4), one 4-load stage group per phase, 3-region lookahead):
//   at end of phase k, in-flight = groups {k-1,k} (8 loads); vmcnt(4) completes
//   group k-1 = region for phase k+2 -> published at barrier k. So region k+1
//   is published at barrier k-1, making phase-k pre-reads of region k+1 legal.
//   Stage group issued in phase k completes by vmcnt at end of k+1 (slack ~1.2
//   phases >> 900-cyc HBM latency). WAR: stage at phase k overwrites region
//   k-1, whose last reads (pre-reads during k-2, consumed by MFMAs in k-1)
//   complete before barrier k-1; stage issues after barrier k-1. Safe.
__global__ void __launch_bounds__(512, 2) gemm_i8_kernel(const signed char* __restrict__ Aq,
                                                         const signed char* __restrict__ Bq,
                                                         const float* __restrict__ xscale,
                                                         const double* __restrict__ wsum,
                                                         float* __restrict__ C,
                                                         int M, int N, int K, int wcount) {
    constexpr int BM = 256, BN = 256, BK = 128;
    __shared__ __align__(16) signed char As[2 * 2 * 16384];
    __shared__ __align__(16) signed char Bs[2 * 2 * 16384];

    const int tid = threadIdx.x;
    const int wave = tid >> 6;
    const int lane = tid & 63;
    const int l32 = lane & 31;
    const int half = lane >> 5;
    const int waveM = (wave & 1) * 128;
    const int waveN = (wave >> 1) * 64;

    // XCD-aware bijective block swizzle (512 blocks, 512 % 8 == 0)
    const int nbx = gridDim.x;
    const int nwg = nbx * gridDim.y;
    const int bid = blockIdx.y * nbx + blockIdx.x;
    const int cpx = nwg >> 3;
    const int swzb = (bid & 7) * cpx + (bid >> 3);
    const int bm = (swzb / nbx) * BM;
    const int bn = (swzb % nbx) * BN;

    v16i acc[4][2];
#pragma unroll
    for (int mt = 0; mt < 4; mt++)
#pragma unroll
        for (int nt = 0; nt < 2; nt++)
#pragma unroll
            for (int r = 0; r < 16; r++) acc[mt][nt][r] = 0;

    // ---- staging precompute: wave w covers segs [w*128, w*128+128) of each region ----
    const int segA0 = wave * 128 + lane;
    const int segA1 = wave * 128 + 64 + lane;
    const int rS0 = segA0 >> 2, rS1 = segA1 >> 2;
    const int cS0 = (segA0 & 3) ^ ((rS0 >> 1) & 3);
    const int cS1 = (segA1 & 3) ^ ((rS1 >> 1) & 3);
    const signed char* aSrc0 = Aq + (size_t)(bm + rS0) * K + cS0 * 16;
    const signed char* aSrc1 = Aq + (size_t)(bm + rS1) * K + cS1 * 16;
    const signed char* bSrc0 = Bq + (size_t)(bn + rS0) * K + cS0 * 16;
    const signed char* bSrc1 = Bq + (size_t)(bn + rS1) * K + cS1 * 16;
    const int dOff0 = segA0 * 16;
    const int dOff1 = segA1 * 16;

#define REG_A(b, H) (As + ((b) * 2 + (H)) * 16384)
#define REG_B(b, H) (Bs + ((b) * 2 + (H)) * 16384)
#define STAGE_A(b, H, k0) {                                            \
        GLOAD_LDS16(aSrc0 + (k0) + (H) * 64, REG_A(b, H) + dOff0);     \
        GLOAD_LDS16(aSrc1 + (k0) + (H) * 64, REG_A(b, H) + dOff1); }
#define STAGE_B(b, H, k0) {                                            \
        GLOAD_LDS16(bSrc0 + (k0) + (H) * 64, REG_B(b, H) + dOff0);     \
        GLOAD_LDS16(bSrc1 + (k0) + (H) * 64, REG_B(b, H) + dOff1); }

    // ---- fragment read offsets (16B-seg units); swizzle dep on l32 only ----
    const int swzl = (l32 >> 1) & 3;
    const int cx0 = half ^ swzl;            // k-chunk parity 0 within half
    const int cx1 = cx0 ^ 2;                // k-chunk parity 1 within half
    const int a0off = (waveM + l32) * 4 + cx0;
    const int a1off = (waveM + l32) * 4 + cx1;
    const int b0off = (waveN + l32) * 4 + cx0;
    const int b1off = (waveN + l32) * 4 + cx1;

#define MFMA_I8(a, b, c) __builtin_amdgcn_mfma_i32_32x32x32_i8(a, b, c, 0, 0, 0)

    // two B-fragment register sets (cur/next alternate per phase)
    v4i bX0 = {}, bX1 = {}, bX2 = {}, bX3 = {};
    v4i bY0 = {}, bY1 = {}, bY2 = {}, bY3 = {};

    // PH: compute region (b,H) using CUR B-set; pre-read B of region (nb,nH)
    // into NXT set; stage one region-pair; vmcnt(4); barrier.
#define PH(b, H, nb, nH, C0, C1, C2, C3, N0, N1, N2, N3, STAGE_STMT)    \
    {                                                                   \
        const v4i* Ap = (const v4i*)REG_A(b, H);                        \
        const v4i* Np = (const v4i*)REG_B(nb, nH);                      \
        v4i aA0 = Ap[a0off];       v4i aA1 = Ap[a0off + 128];           \
        v4i aA2 = Ap[a0off + 256]; v4i aA3 = Ap[a0off + 384];           \
        v4i aB0 = Ap[a1off];       v4i aB1 = Ap[a1off + 128];           \
        v4i aB2 = Ap[a1off + 256]; v4i aB3 = Ap[a1off + 384];           \
        N0 = Np[b0off];  N1 = Np[b0off + 128];                          \
        N2 = Np[b1off];  N3 = Np[b1off + 128];                          \
        STAGE_STMT;                                                     \
        __builtin_amdgcn_s_setprio(1);                                  \
        acc[0][0] = MFMA_I8(aA0, C0, acc[0][0]);                        \
        acc[0][1] = MFMA_I8(aA0, C1, acc[0][1]);                        \
        acc[1][0] = MFMA_I8(aA1, C0, acc[1][0]);                        \
        acc[1][1] = MFMA_I8(aA1, C1, acc[1][1]);                        \
        acc[2][0] = MFMA_I8(aA2, C0, acc[2][0]);                        \
        acc[2][1] = MFMA_I8(aA2, C1, acc[2][1]);                        \
        acc[3][0] = MFMA_I8(aA3, C0, acc[3][0]);                        \
        acc[3][1] = MFMA_I8(aA3, C1, acc[3][1]);                        \
        acc[0][0] = MFMA_I8(aB0, C2, acc[0][0]);                        \
        acc[0][1] = MFMA_I8(aB0, C3, acc[0][1]);                        \
        acc[1][0] = MFMA_I8(aB1, C2, acc[1][0]);                        \
        acc[1][1] = MFMA_I8(aB1, C3, acc[1][1]);                        \
        acc[2][0] = MFMA_I8(aB2, C2, acc[2][0]);                        \
        acc[2][1] = MFMA_I8(aB2, C3, acc[2][1]);                        \
        acc[3][0] = MFMA_I8(aB3, C2, acc[3][0]);                        \
        acc[3][1] = MFMA_I8(aB3, C3, acc[3][1]);                        \
        __builtin_amdgcn_s_setprio(0);                                  \
        asm volatile("s_waitcnt vmcnt(4)" ::: "memory");                \
        __builtin_amdgcn_s_barrier();                                   \
        asm volatile("" ::: "memory");                                  \
    }

    // ---- prologue: stage P0, P1, P2; publish P0+P1; pre-read P0's B-frags ----
    STAGE_A(0, 0, 0); STAGE_B(0, 0, 0);
    STAGE_A(0, 1, 0); STAGE_B(0, 1, 0);
    STAGE_A(1, 0, BK); STAGE_B(1, 0, BK);
    asm volatile("s_waitcnt vmcnt(4)" ::: "memory");
    __builtin_amdgcn_s_barrier();
    asm volatile("" ::: "memory");
    {
        const v4i* Bp = (const v4i*)REG_B(0, 0);
        bX0 = Bp[b0off];  bX1 = Bp[b0off + 128];
        bX2 = Bp[b1off];  bX3 = Bp[b1off + 128];
    }

    const int kclamp = K - BK;   // clamp garbage prefetch of tiles past K in-bounds
    const int niter = K / (2 * BK);
#pragma unroll 1
    for (int it = 0; it < niter; ++it) {
        int k0O = (2 * it + 1) * BK;                                  // always <= K-BK
        int k0E2 = (2 * it + 2) * BK; if (k0E2 > kclamp) k0E2 = kclamp;
        int k0O2 = (2 * it + 3) * BK; if (k0O2 > kclamp) k0O2 = kclamp;

        PH(0, 0, 0, 1, bX0, bX1, bX2, bX3, bY0, bY1, bY2, bY3,
           STAGE_A(1, 1, k0O);  STAGE_B(1, 1, k0O))
        PH(0, 1, 1, 0, bY0, bY1, bY2, bY3, bX0, bX1, bX2, bX3,
           STAGE_A(0, 0, k0E2); STAGE_B(0, 0, k0E2))
        PH(1, 0, 1, 1, bX0, bX1, bX2, bX3, bY0, bY1, bY2, bY3,
           STAGE_A(0, 1, k0E2); STAGE_B(0, 1, k0E2))
        PH(1, 1, 0, 0, bY0, bY1, bY2, bY3, bX0, bX1, bX2, bX3,
           STAGE_A(1, 0, k0O2); STAGE_B(1, 0, k0O2))
    }

    // drain zombie global_load_lds before LDS deallocates at endpgm
    asm volatile("s_waitcnt vmcnt(0)" ::: "memory");

    // ---- epilogue: 32x32 C/D layout: col = lane&31, row = (r&3) + 8*(r>>2) + 4*half
    float wsf = (float)(wsum[0] / (double)wcount) + EPS_F;
    const float wk = wsf / 127.0f;
#pragma unroll
    for (int mt = 0; mt < 4; mt++) {
        int rowbase = bm + waveM + mt * 32 + 4 * half;
#pragma unroll
        for (int r = 0; r < 16; r++) {
            int gm = rowbase + (r & 3) + 8 * (r >> 2);
            float s = xscale[gm] * wk;
            float* crow = C + (size_t)gm * N + bn + waveN + l32;
            crow[0]  = (float)acc[mt][0][r] * s;
            crow[32] = (float)acc[mt][1][r] * s;
        }
    }
}

extern "C" void kernel_launch(void* const* d_in, const int* in_sizes, int n_in,
                              void* d_out, int out_size, void* d_ws, size_t ws_size,
                              hipStream_t stream) {
    const float* x = (const float*)d_in[0];
    const float* w = (const float*)d_in[1];
    float* y = (float*)d_out;

    const int K = 4096, N = 4096;
    const int M = in_sizes[0] / K;       // 8192
    const int wcount = in_sizes[1];      // N*K

    double* wsum = (double*)d_ws;
    float* xscale = (float*)((char*)d_ws + 256);
    signed char* xq = (signed char*)((char*)d_ws + 256 + 65536);
    signed char* wq = xq + (size_t)M * K;

    hipMemsetAsync(wsum, 0, sizeof(double), stream);
    wabs_xquant_kernel<<<1024 + M, 256, 0, stream>>>(w, wsum, wcount / 4, x, xq, xscale, K);
    wquant_kernel<<<2048, 256, 0, stream>>>(w, wsum, wq, wcount / 4, wcount);
    dim3 grid(N / 256, M / 256);
    gemm_i8_kernel<<<grid, 512, 0, stream>>>(xq, wq, xscale, wsum, y, M, N, K, wcount);
}

// Round 6
// 417.579 us; speedup vs baseline: 1.0304x; 1.0304x over previous
//
#include <hip/hip_runtime.h>

typedef int v4i __attribute__((ext_vector_type(4)));
typedef int v16i __attribute__((ext_vector_type(16)));

#define EPS_F 1e-8f

#define GLOAD_LDS16(g, l)                                              \
    __builtin_amdgcn_global_load_lds(                                  \
        (const __attribute__((address_space(1))) void*)(g),            \
        (__attribute__((address_space(3))) void*)(l), 16, 0, 0)

// ---------------- kernel 1: fused |w| partial sums (blocks [0,1024)) + per-token x quant ----------------
// wabs writes per-block PARTIAL sums (no atomics, no memset node needed);
// wquant reduces them (r5 post-mortem: 1024 serialized same-address fp64
// atomicAdds were a hidden serialization suspect on the quant side).
__global__ void __launch_bounds__(256) wabs_xquant_kernel(const float* __restrict__ w,
                                                          double* __restrict__ wpart, int n4,
                                                          const float* __restrict__ x,
                                                          signed char* __restrict__ xq,
                                                          float* __restrict__ xscale, int K) {
    if (blockIdx.x < 1024) {
        // ---- |w| fp64 partial sum ----
        const float4* w4 = (const float4*)w;
        double s = 0.0;
        int idx = blockIdx.x * 256 + threadIdx.x;
        int stride = 1024 * 256;
        for (int i = idx; i < n4; i += stride) {
            float4 v = w4[i];
            s += (double)fabsf(v.x) + (double)fabsf(v.y) +
                 (double)fabsf(v.z) + (double)fabsf(v.w);
        }
        for (int off = 32; off > 0; off >>= 1)
            s += __shfl_down(s, off);
        __shared__ double smd[4];
        if ((threadIdx.x & 63) == 0) smd[threadIdx.x >> 6] = s;
        __syncthreads();
        if (threadIdx.x == 0) {
            wpart[blockIdx.x] = smd[0] + smd[1] + smd[2] + smd[3];
        }
    } else {
        // ---- per-token int8 activation quant, one row per block ----
        int row = blockIdx.x - 1024;
        const float4* xr = (const float4*)(x + (size_t)row * K);
        unsigned int* qr = (unsigned int*)(xq + (size_t)row * K);
        int t = threadIdx.x;
        float4 v[4];
        float mx = 0.0f;
#pragma unroll
        for (int j = 0; j < 4; j++) {
            v[j] = xr[t + j * 256];
            mx = fmaxf(mx, fmaxf(fmaxf(fabsf(v[j].x), fabsf(v[j].y)),
                                 fmaxf(fabsf(v[j].z), fabsf(v[j].w))));
        }
        for (int off = 32; off > 0; off >>= 1)
            mx = fmaxf(mx, __shfl_down(mx, off));
        __shared__ float smf[4];
        if ((t & 63) == 0) smf[t >> 6] = mx;
        __syncthreads();
        float scale = fmaxf(fmaxf(fmaxf(smf[0], smf[1]), fmaxf(smf[2], smf[3])), EPS_F);
        float inv = 127.0f / scale;
#pragma unroll
        for (int j = 0; j < 4; j++) {
            int q0 = min(127, max(-127, (int)rintf(v[j].x * inv)));
            int q1 = min(127, max(-127, (int)rintf(v[j].y * inv)));
            int q2 = min(127, max(-127, (int)rintf(v[j].z * inv)));
            int q3 = min(127, max(-127, (int)rintf(v[j].w * inv)));
            qr[t + j * 256] = (q0 & 0xff) | ((q1 & 0xff) << 8) | ((q2 & 0xff) << 16) | ((q3 & 0xff) << 24);
        }
        if (t == 0) xscale[row] = scale;
    }
}

// ---------------- kernel 2: reduce wabs partials + ternary-quantize W -> int8 ----------------
__global__ void __launch_bounds__(256) wquant_kernel(const float* __restrict__ w,
                                                     const double* __restrict__ wpart,
                                                     double* __restrict__ wsum,
                                                     signed char* __restrict__ wq,
                                                     int n4, int n) {
    // every block reduces the 1024 partials (8KB, L2-hot, deterministic)
    int t = threadIdx.x;
    double s = wpart[t] + wpart[t + 256] + wpart[t + 512] + wpart[t + 768];
    for (int off = 32; off > 0; off >>= 1)
        s += __shfl_down(s, off);
    __shared__ double smd[4];
    if ((t & 63) == 0) smd[t >> 6] = s;
    __syncthreads();
    double total = smd[0] + smd[1] + smd[2] + smd[3];
    if (blockIdx.x == 0 && t == 0) wsum[0] = total;   // publish for gemm epilogue

    float wsf = (float)(total / (double)n) + EPS_F;
    float inv = 1.0f / wsf;
    const float4* w4 = (const float4*)w;
    unsigned int* q4 = (unsigned int*)wq;
    int idx = blockIdx.x * 256 + t;
    int stride = gridDim.x * 256;
    for (int i = idx; i < n4; i += stride) {
        float4 v = w4[i];
        int q0 = min(1, max(-1, (int)rintf(v.x * inv)));
        int q1 = min(1, max(-1, (int)rintf(v.y * inv)));
        int q2 = min(1, max(-1, (int)rintf(v.z * inv)));
        int q3 = min(1, max(-1, (int)rintf(v.w * inv)));
        q4[i] = (q0 & 0xff) | ((q1 & 0xff) << 8) | ((q2 & 0xff) << 16) | ((q3 & 0xff) << 24);
    }
}

// ---------------- kernel 3: int8 MFMA GEMM, 256x256 tile, 4-phase / 1-barrier ----------------
// EXACT r4 structure (best measured: 161 us, MfmaUtil 37.6) -- r5's B-reg
// double-buffer regressed (177 us, 32.2%) and is reverted.
// 512 threads = 8 waves (2M x 4N). Per-wave output 128x64 = 4x2 tiles of 32x32.
// BK=128. LDS: [buf(2)][A/B][khalf(2)] regions of 16KB = 128KB total (1 block/CU).
// Region layout: seg(row, c) = row*4 + (c ^ ((row>>1)&3)) -> bank-slot seg&7 covers
// all 8 slots per 8 rows -> conflict-free ds_read_b128.
// ONE barrier per phase: s_barrier does not wait on issued MFMAs, so phase-n+1
// ds_reads overlap phase-n MFMA drain. WAR: every ds_read feeds an MFMA in the
// same phase => reads complete before the wave reaches the end barrier; the
// overwriting stage is issued after it. RAW: vmcnt(8) at phase end completes
// the 3-phase-old stage group; barrier publishes; fence stops read hoist.
__global__ void __launch_bounds__(512, 2) gemm_i8_kernel(const signed char* __restrict__ Aq,
                                                         const signed char* __restrict__ Bq,
                                                         const float* __restrict__ xscale,
                                                         const double* __restrict__ wsum,
                                                         float* __restrict__ C,
                                                         int M, int N, int K, int wcount) {
    constexpr int BM = 256, BN = 256, BK = 128;
    __shared__ __align__(16) signed char As[2 * 2 * 16384];
    __shared__ __align__(16) signed char Bs[2 * 2 * 16384];

    const int tid = threadIdx.x;
    const int wave = tid >> 6;
    const int lane = tid & 63;
    const int l32 = lane & 31;
    const int half = lane >> 5;
    const int waveM = (wave & 1) * 128;
    const int waveN = (wave >> 1) * 64;

    // XCD-aware bijective block swizzle (512 blocks, 512 % 8 == 0)
    const int nbx = gridDim.x;
    const int nwg = nbx * gridDim.y;
    const int bid = blockIdx.y * nbx + blockIdx.x;
    const int cpx = nwg >> 3;
    const int swzb = (bid & 7) * cpx + (bid >> 3);
    const int bm = (swzb / nbx) * BM;
    const int bn = (swzb % nbx) * BN;

    v16i acc[4][2];
#pragma unroll
    for (int mt = 0; mt < 4; mt++)
#pragma unroll
        for (int nt = 0; nt < 2; nt++)
#pragma unroll
            for (int r = 0; r < 16; r++) acc[mt][nt][r] = 0;

    // ---- staging precompute: wave w covers segs [w*128, w*128+128) of each region ----
    const int segA0 = wave * 128 + lane;
    const int segA1 = wave * 128 + 64 + lane;
    const int rS0 = segA0 >> 2, rS1 = segA1 >> 2;
    const int cS0 = (segA0 & 3) ^ ((rS0 >> 1) & 3);
    const int cS1 = (segA1 & 3) ^ ((rS1 >> 1) & 3);
    const signed char* aSrc0 = Aq + (size_t)(bm + rS0) * K + cS0 * 16;
    const signed char* aSrc1 = Aq + (size_t)(bm + rS1) * K + cS1 * 16;
    const signed char* bSrc0 = Bq + (size_t)(bn + rS0) * K + cS0 * 16;
    const signed char* bSrc1 = Bq + (size_t)(bn + rS1) * K + cS1 * 16;
    const int dOff0 = segA0 * 16;
    const int dOff1 = segA1 * 16;

#define REG_A(b, H) (As + ((b) * 2 + (H)) * 16384)
#define REG_B(b, H) (Bs + ((b) * 2 + (H)) * 16384)
#define STAGE_A(b, H, k0) {                                            \
        GLOAD_LDS16(aSrc0 + (k0) + (H) * 64, REG_A(b, H) + dOff0);     \
        GLOAD_LDS16(aSrc1 + (k0) + (H) * 64, REG_A(b, H) + dOff1); }
#define STAGE_B(b, H, k0) {                                            \
        GLOAD_LDS16(bSrc0 + (k0) + (H) * 64, REG_B(b, H) + dOff0);     \
        GLOAD_LDS16(bSrc1 + (k0) + (H) * 64, REG_B(b, H) + dOff1); }

    // ---- fragment read offsets (16B-seg units); swizzle dep on l32 only ----
    const int swzl = (l32 >> 1) & 3;
    const int cx0 = half ^ swzl;            // k-chunk parity 0 within half
    const int cx1 = cx0 ^ 2;                // k-chunk parity 1 within half
    const int a0off = (waveM + l32) * 4 + cx0;
    const int a1off = (waveM + l32) * 4 + cx1;
    const int b0off = (waveN + l32) * 4 + cx0;
    const int b1off = (waveN + l32) * 4 + cx1;

#define MFMA_I8(a, b, c) __builtin_amdgcn_mfma_i32_32x32x32_i8(a, b, c, 0, 0, 0)

#define PHASE1B(b, H, STAGE_STMT)                                       \
    {                                                                   \
        const v4i* Ap = (const v4i*)REG_A(b, H);                        \
        const v4i* Bp = (const v4i*)REG_B(b, H);                        \
        v4i aA0 = Ap[a0off];       v4i aA1 = Ap[a0off + 128];           \
        v4i aA2 = Ap[a0off + 256]; v4i aA3 = Ap[a0off + 384];           \
        v4i bA0 = Bp[b0off];       v4i bA1 = Bp[b0off + 128];           \
        v4i aB0 = Ap[a1off];       v4i aB1 = Ap[a1off + 128];           \
        v4i aB2 = Ap[a1off + 256]; v4i aB3 = Ap[a1off + 384];           \
        v4i bB0 = Bp[b1off];       v4i bB1 = Bp[b1off + 128];           \
        STAGE_STMT;                                                     \
        __builtin_amdgcn_s_setprio(1);                                  \
        acc[0][0] = MFMA_I8(aA0, bA0, acc[0][0]);                       \
        acc[0][1] = MFMA_I8(aA0, bA1, acc[0][1]);                       \
        acc[1][0] = MFMA_I8(aA1, bA0, acc[1][0]);                       \
        acc[1][1] = MFMA_I8(aA1, bA1, acc[1][1]);                       \
        acc[2][0] = MFMA_I8(aA2, bA0, acc[2][0]);                       \
        acc[2][1] = MFMA_I8(aA2, bA1, acc[2][1]);                       \
        acc[3][0] = MFMA_I8(aA3, bA0, acc[3][0]);                       \
        acc[3][1] = MFMA_I8(aA3, bA1, acc[3][1]);                       \
        acc[0][0] = MFMA_I8(aB0, bB0, acc[0][0]);                       \
        acc[0][1] = MFMA_I8(aB0, bB1, acc[0][1]);                       \
        acc[1][0] = MFMA_I8(aB1, bB0, acc[1][0]);                       \
        acc[1][1] = MFMA_I8(aB1, bB1, acc[1][1]);                       \
        acc[2][0] = MFMA_I8(aB2, bB0, acc[2][0]);                       \
        acc[2][1] = MFMA_I8(aB2, bB1, acc[2][1]);                       \
        acc[3][0] = MFMA_I8(aB3, bB0, acc[3][0]);                       \
        acc[3][1] = MFMA_I8(aB3, bB1, acc[3][1]);                       \
        __builtin_amdgcn_s_setprio(0);                                  \
        asm volatile("s_waitcnt vmcnt(8)" ::: "memory");                \
        __builtin_amdgcn_s_barrier();                                   \
        asm volatile("" ::: "memory");                                  \
    }

    // ---- prologue: stage regions for P0, P1, P2 (3-phase lookahead) ----
    STAGE_A(0, 0, 0); STAGE_B(0, 0, 0);
    STAGE_A(0, 1, 0); STAGE_B(0, 1, 0);
    STAGE_A(1, 0, BK); STAGE_B(1, 0, BK);
    asm volatile("s_waitcnt vmcnt(8)" ::: "memory");
    __builtin_amdgcn_s_barrier();
    asm volatile("" ::: "memory");

    const int kclamp = K - BK;   // clamp garbage prefetch of tiles past K in-bounds
    const int niter = K / (2 * BK);
#pragma unroll 1
    for (int it = 0; it < niter; ++it) {
        int k0O = (2 * it + 1) * BK;                                  // always <= K-BK
        int k0E2 = (2 * it + 2) * BK; if (k0E2 > kclamp) k0E2 = kclamp;
        int k0O2 = (2 * it + 3) * BK; if (k0O2 > kclamp) k0O2 = kclamp;

        PHASE1B(0, 0, STAGE_A(1, 1, k0O);  STAGE_B(1, 1, k0O))
        PHASE1B(0, 1, STAGE_A(0, 0, k0E2); STAGE_B(0, 0, k0E2))
        PHASE1B(1, 0, STAGE_A(0, 1, k0E2); STAGE_B(0, 1, k0E2))
        PHASE1B(1, 1, STAGE_A(1, 0, k0O2); STAGE_B(1, 0, k0O2))
    }

    // drain zombie global_load_lds before LDS deallocates at endpgm
    asm volatile("s_waitcnt vmcnt(0)" ::: "memory");

    // ---- epilogue: 32x32 C/D layout: col = lane&31, row = (r&3) + 8*(r>>2) + 4*half
    float wsf = (float)(wsum[0] / (double)wcount) + EPS_F;
    const float wk = wsf / 127.0f;
#pragma unroll
    for (int mt = 0; mt < 4; mt++) {
        int rowbase = bm + waveM + mt * 32 + 4 * half;
#pragma unroll
        for (int r = 0; r < 16; r++) {
            int gm = rowbase + (r & 3) + 8 * (r >> 2);
            float s = xscale[gm] * wk;
            float* crow = C + (size_t)gm * N + bn + waveN + l32;
            crow[0]  = (float)acc[mt][0][r] * s;
            crow[32] = (float)acc[mt][1][r] * s;
        }
    }
}

extern "C" void kernel_launch(void* const* d_in, const int* in_sizes, int n_in,
                              void* d_out, int out_size, void* d_ws, size_t ws_size,
                              hipStream_t stream) {
    const float* x = (const float*)d_in[0];
    const float* w = (const float*)d_in[1];
    float* y = (float*)d_out;

    const int K = 4096, N = 4096;
    const int M = in_sizes[0] / K;       // 8192
    const int wcount = in_sizes[1];      // N*K

    // workspace layout
    double* wsum = (double*)d_ws;                                  // 8 B
    float* xscale = (float*)((char*)d_ws + 256);                   // 32 KB
    double* wpart = (double*)((char*)d_ws + 65536);                // 8 KB
    signed char* xq = (signed char*)((char*)d_ws + 131072);
    signed char* wq = xq + (size_t)M * K;

    wabs_xquant_kernel<<<1024 + M, 256, 0, stream>>>(w, wpart, wcount / 4, x, xq, xscale, K);
    wquant_kernel<<<2048, 256, 0, stream>>>(w, wpart, wsum, wq, wcount / 4, wcount);
    dim3 grid(N / 256, M / 256);
    gemm_i8_kernel<<<grid, 512, 0, stream>>>(xq, wq, xscale, wsum, y, M, N, K, wcount);
}

// Round 7
// 411.793 us; speedup vs baseline: 1.0449x; 1.0141x over previous
//
#include <hip/hip_runtime.h>

typedef int v4i __attribute__((ext_vector_type(4)));
typedef int v16i __attribute__((ext_vector_type(16)));

#define EPS_F 1e-8f

#define GLOAD_LDS16(g, l)                                              \
    __builtin_amdgcn_global_load_lds(                                  \
        (const __attribute__((address_space(1))) void*)(g),            \
        (__attribute__((address_space(3))) void*)(l), 16, 0, 0)

// ---------------- kernel 1: fused |w| partial sums (blocks [0,1024)) + per-token x quant ----------------
// r6 post-mortem: quant side ~255us vs ~49us roofline across 4 rounds = latency-
// bound (1 load in flight per thread in rolled loops) + block-granularity tax.
// Fix: xquant = one WAVE per row, 16 independent dwordx4 loads in flight, shfl_xor
// reduce, no LDS/syncthreads; wabs = unroll 4 (16 iters exact) for 4-deep MLP.
__global__ void __launch_bounds__(256) wabs_xquant_kernel(const float* __restrict__ w,
                                                          double* __restrict__ wpart, int n4,
                                                          const float* __restrict__ x,
                                                          signed char* __restrict__ xq,
                                                          float* __restrict__ xscale, int K) {
    if (blockIdx.x < 1024) {
        // ---- |w| fp64 partial sum (16 iterations exactly; unroll 4) ----
        const float4* w4 = (const float4*)w;
        double s = 0.0;
        int idx = blockIdx.x * 256 + threadIdx.x;
        int stride = 1024 * 256;
#pragma unroll 4
        for (int i = idx; i < n4; i += stride) {
            float4 v = w4[i];
            s += (double)fabsf(v.x) + (double)fabsf(v.y) +
                 (double)fabsf(v.z) + (double)fabsf(v.w);
        }
        for (int off = 32; off > 0; off >>= 1)
            s += __shfl_down(s, off);
        __shared__ double smd[4];
        if ((threadIdx.x & 63) == 0) smd[threadIdx.x >> 6] = s;
        __syncthreads();
        if (threadIdx.x == 0) {
            wpart[blockIdx.x] = smd[0] + smd[1] + smd[2] + smd[3];
        }
    } else {
        // ---- per-token int8 activation quant: one wave per row, 4 rows/block ----
        const int wv = threadIdx.x >> 6;
        const int l = threadIdx.x & 63;
        const int row = (blockIdx.x - 1024) * 4 + wv;
        const float4* xr = (const float4*)(x + (size_t)row * K);
        unsigned int* qr = (unsigned int*)(xq + (size_t)row * K);
        float4 v[16];
        float mx = 0.0f;
#pragma unroll
        for (int i = 0; i < 16; i++) {
            v[i] = xr[l + i * 64];
            mx = fmaxf(mx, fmaxf(fmaxf(fabsf(v[i].x), fabsf(v[i].y)),
                                 fmaxf(fabsf(v[i].z), fabsf(v[i].w))));
        }
#pragma unroll
        for (int off = 32; off > 0; off >>= 1)
            mx = fmaxf(mx, __shfl_xor(mx, off));
        float scale = fmaxf(mx, EPS_F);
        float inv = 127.0f / scale;
#pragma unroll
        for (int i = 0; i < 16; i++) {
            int q0 = min(127, max(-127, (int)rintf(v[i].x * inv)));
            int q1 = min(127, max(-127, (int)rintf(v[i].y * inv)));
            int q2 = min(127, max(-127, (int)rintf(v[i].z * inv)));
            int q3 = min(127, max(-127, (int)rintf(v[i].w * inv)));
            qr[l + i * 64] = (q0 & 0xff) | ((q1 & 0xff) << 8) | ((q2 & 0xff) << 16) | ((q3 & 0xff) << 24);
        }
        if (l == 0) xscale[row] = scale;
    }
}

// ---------------- kernel 2: reduce wabs partials + ternary-quantize W -> int8 ----------------
__global__ void __launch_bounds__(256) wquant_kernel(const float* __restrict__ w,
                                                     const double* __restrict__ wpart,
                                                     double* __restrict__ wsum,
                                                     signed char* __restrict__ wq,
                                                     int n4, int n) {
    // every block reduces the 1024 partials (8KB, L2-hot, deterministic)
    int t = threadIdx.x;
    double s = wpart[t] + wpart[t + 256] + wpart[t + 512] + wpart[t + 768];
    for (int off = 32; off > 0; off >>= 1)
        s += __shfl_down(s, off);
    __shared__ double smd[4];
    if ((t & 63) == 0) smd[t >> 6] = s;
    __syncthreads();
    double total = smd[0] + smd[1] + smd[2] + smd[3];
    if (blockIdx.x == 0 && t == 0) wsum[0] = total;   // publish for gemm epilogue

    float wsf = (float)(total / (double)n) + EPS_F;
    float inv = 1.0f / wsf;
    const float4* w4 = (const float4*)w;
    unsigned int* q4 = (unsigned int*)wq;
    int idx = blockIdx.x * 256 + t;
    int stride = gridDim.x * 256;
#pragma unroll 4
    for (int i = idx; i < n4; i += stride) {
        float4 v = w4[i];
        int q0 = min(1, max(-1, (int)rintf(v.x * inv)));
        int q1 = min(1, max(-1, (int)rintf(v.y * inv)));
        int q2 = min(1, max(-1, (int)rintf(v.z * inv)));
        int q3 = min(1, max(-1, (int)rintf(v.w * inv)));
        q4[i] = (q0 & 0xff) | ((q1 & 0xff) << 8) | ((q2 & 0xff) << 16) | ((q3 & 0xff) << 24);
    }
}

// ---------------- kernel 3: int8 MFMA GEMM, 256x256 tile, 4-phase / 1-barrier ----------------
// EXACT r4/r6 structure (best measured: 161-162 us, MfmaUtil ~37).
// 512 threads = 8 waves (2M x 4N). Per-wave output 128x64 = 4x2 tiles of 32x32.
// BK=128. LDS: [buf(2)][A/B][khalf(2)] regions of 16KB = 128KB total (1 block/CU).
// Region layout: seg(row, c) = row*4 + (c ^ ((row>>1)&3)) -> bank-slot seg&7 covers
// all 8 slots per 8 rows -> conflict-free ds_read_b128.
// ONE barrier per phase: s_barrier does not wait on issued MFMAs, so phase-n+1
// ds_reads overlap phase-n MFMA drain. WAR: every ds_read feeds an MFMA in the
// same phase => reads complete before the wave reaches the end barrier; the
// overwriting stage is issued after it. RAW: vmcnt(8) at phase end completes
// the 3-phase-old stage group; barrier publishes; fence stops read hoist.
__global__ void __launch_bounds__(512, 2) gemm_i8_kernel(const signed char* __restrict__ Aq,
                                                         const signed char* __restrict__ Bq,
                                                         const float* __restrict__ xscale,
                                                         const double* __restrict__ wsum,
                                                         float* __restrict__ C,
                                                         int M, int N, int K, int wcount) {
    constexpr int BM = 256, BN = 256, BK = 128;
    __shared__ __align__(16) signed char As[2 * 2 * 16384];
    __shared__ __align__(16) signed char Bs[2 * 2 * 16384];

    const int tid = threadIdx.x;
    const int wave = tid >> 6;
    const int lane = tid & 63;
    const int l32 = lane & 31;
    const int half = lane >> 5;
    const int waveM = (wave & 1) * 128;
    const int waveN = (wave >> 1) * 64;

    // XCD-aware bijective block swizzle (512 blocks, 512 % 8 == 0)
    const int nbx = gridDim.x;
    const int nwg = nbx * gridDim.y;
    const int bid = blockIdx.y * nbx + blockIdx.x;
    const int cpx = nwg >> 3;
    const int swzb = (bid & 7) * cpx + (bid >> 3);
    const int bm = (swzb / nbx) * BM;
    const int bn = (swzb % nbx) * BN;

    v16i acc[4][2];
#pragma unroll
    for (int mt = 0; mt < 4; mt++)
#pragma unroll
        for (int nt = 0; nt < 2; nt++)
#pragma unroll
            for (int r = 0; r < 16; r++) acc[mt][nt][r] = 0;

    // ---- staging precompute: wave w covers segs [w*128, w*128+128) of each region ----
    const int segA0 = wave * 128 + lane;
    const int segA1 = wave * 128 + 64 + lane;
    const int rS0 = segA0 >> 2, rS1 = segA1 >> 2;
    const int cS0 = (segA0 & 3) ^ ((rS0 >> 1) & 3);
    const int cS1 = (segA1 & 3) ^ ((rS1 >> 1) & 3);
    const signed char* aSrc0 = Aq + (size_t)(bm + rS0) * K + cS0 * 16;
    const signed char* aSrc1 = Aq + (size_t)(bm + rS1) * K + cS1 * 16;
    const signed char* bSrc0 = Bq + (size_t)(bn + rS0) * K + cS0 * 16;
    const signed char* bSrc1 = Bq + (size_t)(bn + rS1) * K + cS1 * 16;
    const int dOff0 = segA0 * 16;
    const int dOff1 = segA1 * 16;

#define REG_A(b, H) (As + ((b) * 2 + (H)) * 16384)
#define REG_B(b, H) (Bs + ((b) * 2 + (H)) * 16384)
#define STAGE_A(b, H, k0) {                                            \
        GLOAD_LDS16(aSrc0 + (k0) + (H) * 64, REG_A(b, H) + dOff0);     \
        GLOAD_LDS16(aSrc1 + (k0) + (H) * 64, REG_A(b, H) + dOff1); }
#define STAGE_B(b, H, k0) {                                            \
        GLOAD_LDS16(bSrc0 + (k0) + (H) * 64, REG_B(b, H) + dOff0);     \
        GLOAD_LDS16(bSrc1 + (k0) + (H) * 64, REG_B(b, H) + dOff1); }

    // ---- fragment read offsets (16B-seg units); swizzle dep on l32 only ----
    const int swzl = (l32 >> 1) & 3;
    const int cx0 = half ^ swzl;            // k-chunk parity 0 within half
    const int cx1 = cx0 ^ 2;                // k-chunk parity 1 within half
    const int a0off = (waveM + l32) * 4 + cx0;
    const int a1off = (waveM + l32) * 4 + cx1;
    const int b0off = (waveN + l32) * 4 + cx0;
    const int b1off = (waveN + l32) * 4 + cx1;

#define MFMA_I8(a, b, c) __builtin_amdgcn_mfma_i32_32x32x32_i8(a, b, c, 0, 0, 0)

#define PHASE1B(b, H, STAGE_STMT)                                       \
    {                                                                   \
        const v4i* Ap = (const v4i*)REG_A(b, H);                        \
        const v4i* Bp = (const v4i*)REG_B(b, H);                        \
        v4i aA0 = Ap[a0off];       v4i aA1 = Ap[a0off + 128];           \
        v4i aA2 = Ap[a0off + 256]; v4i aA3 = Ap[a0off + 384];           \
        v4i bA0 = Bp[b0off];       v4i bA1 = Bp[b0off + 128];           \
        v4i aB0 = Ap[a1off];       v4i aB1 = Ap[a1off + 128];           \
        v4i aB2 = Ap[a1off + 256]; v4i aB3 = Ap[a1off + 384];           \
        v4i bB0 = Bp[b1off];       v4i bB1 = Bp[b1off + 128];           \
        STAGE_STMT;                                                     \
        __builtin_amdgcn_s_setprio(1);                                  \
        acc[0][0] = MFMA_I8(aA0, bA0, acc[0][0]);                       \
        acc[0][1] = MFMA_I8(aA0, bA1, acc[0][1]);                       \
        acc[1][0] = MFMA_I8(aA1, bA0, acc[1][0]);                       \
        acc[1][1] = MFMA_I8(aA1, bA1, acc[1][1]);                       \
        acc[2][0] = MFMA_I8(aA2, bA0, acc[2][0]);                       \
        acc[2][1] = MFMA_I8(aA2, bA1, acc[2][1]);                       \
        acc[3][0] = MFMA_I8(aA3, bA0, acc[3][0]);                       \
        acc[3][1] = MFMA_I8(aA3, bA1, acc[3][1]);                       \
        acc[0][0] = MFMA_I8(aB0, bB0, acc[0][0]);                       \
        acc[0][1] = MFMA_I8(aB0, bB1, acc[0][1]);                       \
        acc[1][0] = MFMA_I8(aB1, bB0, acc[1][0]);                       \
        acc[1][1] = MFMA_I8(aB1, bB1, acc[1][1]);                       \
        acc[2][0] = MFMA_I8(aB2, bB0, acc[2][0]);                       \
        acc[2][1] = MFMA_I8(aB2, bB1, acc[2][1]);                       \
        acc[3][0] = MFMA_I8(aB3, bB0, acc[3][0]);                       \
        acc[3][1] = MFMA_I8(aB3, bB1, acc[3][1]);                       \
        __builtin_amdgcn_s_setprio(0);                                  \
        asm volatile("s_waitcnt vmcnt(8)" ::: "memory");                \
        __builtin_amdgcn_s_barrier();                                   \
        asm volatile("" ::: "memory");                                  \
    }

    // ---- prologue: stage regions for P0, P1, P2 (3-phase lookahead) ----
    STAGE_A(0, 0, 0); STAGE_B(0, 0, 0);
    STAGE_A(0, 1, 0); STAGE_B(0, 1, 0);
    STAGE_A(1, 0, BK); STAGE_B(1, 0, BK);
    asm volatile("s_waitcnt vmcnt(8)" ::: "memory");
    __builtin_amdgcn_s_barrier();
    asm volatile("" ::: "memory");

    const int kclamp = K - BK;   // clamp garbage prefetch of tiles past K in-bounds
    const int niter = K / (2 * BK);
#pragma unroll 1
    for (int it = 0; it < niter; ++it) {
        int k0O = (2 * it + 1) * BK;                                  // always <= K-BK
        int k0E2 = (2 * it + 2) * BK; if (k0E2 > kclamp) k0E2 = kclamp;
        int k0O2 = (2 * it + 3) * BK; if (k0O2 > kclamp) k0O2 = kclamp;

        PHASE1B(0, 0, STAGE_A(1, 1, k0O);  STAGE_B(1, 1, k0O))
        PHASE1B(0, 1, STAGE_A(0, 0, k0E2); STAGE_B(0, 0, k0E2))
        PHASE1B(1, 0, STAGE_A(0, 1, k0E2); STAGE_B(0, 1, k0E2))
        PHASE1B(1, 1, STAGE_A(1, 0, k0O2); STAGE_B(1, 0, k0O2))
    }

    // drain zombie global_load_lds before LDS deallocates at endpgm
    asm volatile("s_waitcnt vmcnt(0)" ::: "memory");

    // ---- epilogue: 32x32 C/D layout: col = lane&31, row = (r&3) + 8*(r>>2) + 4*half
    float wsf = (float)(wsum[0] / (double)wcount) + EPS_F;
    const float wk = wsf / 127.0f;
#pragma unroll
    for (int mt = 0; mt < 4; mt++) {
        int rowbase = bm + waveM + mt * 32 + 4 * half;
#pragma unroll
        for (int r = 0; r < 16; r++) {
            int gm = rowbase + (r & 3) + 8 * (r >> 2);
            float s = xscale[gm] * wk;
            float* crow = C + (size_t)gm * N + bn + waveN + l32;
            crow[0]  = (float)acc[mt][0][r] * s;
            crow[32] = (float)acc[mt][1][r] * s;
        }
    }
}

extern "C" void kernel_launch(void* const* d_in, const int* in_sizes, int n_in,
                              void* d_out, int out_size, void* d_ws, size_t ws_size,
                              hipStream_t stream) {
    const float* x = (const float*)d_in[0];
    const float* w = (const float*)d_in[1];
    float* y = (float*)d_out;

    const int K = 4096, N = 4096;
    const int M = in_sizes[0] / K;       // 8192
    const int wcount = in_sizes[1];      // N*K

    // workspace layout
    double* wsum = (double*)d_ws;                                  // 8 B
    float* xscale = (float*)((char*)d_ws + 256);                   // 32 KB
    double* wpart = (double*)((char*)d_ws + 65536);                // 8 KB
    signed char* xq = (signed char*)((char*)d_ws + 131072);
    signed char* wq = xq + (size_t)M * K;

    wabs_xquant_kernel<<<1024 + M / 4, 256, 0, stream>>>(w, wpart, wcount / 4, x, xq, xscale, K);
    wquant_kernel<<<2048, 256, 0, stream>>>(w, wpart, wsum, wq, wcount / 4, wcount);
    dim3 grid(N / 256, M / 256);
    gemm_i8_kernel<<<grid, 512, 0, stream>>>(xq, wq, xscale, wsum, y, M, N, K, wcount);
}